// Round 7
// baseline (159.522 us; speedup 1.0000x reference)
//
#include <hip/hip_runtime.h>
#include <math.h>

// LinearAttention: T=1024, D=256, H=256.  R7: 2 kernels, no memset.
// combine() is NOT associative; replicate JAX's odd-even bracketing via a
// bitpacked mask (proven R3/R6). s0=z0=0 -> s_t = sum_j W[t][j] k_j v_j^T;
// denom_t = (sum_j W[t][j] Ksum_j) * Qsum_t. Total mask nnz ~ O(T) (measured:
// mega FETCH ~= inputs) -> attention = sparse gather.
// K1 qkvs_mask grid(257): 256 MFMA projection blocks (Ksum -> 4 partial slots,
//   no atomic) + 1 mask-build block (256-thr port of proven R3 code) -> Mb.
// K2 attn_mlp grid(256)x512: 4 rows/block on ALL CUs; 2 waves/row sparse
//   gather; fused 3-layer mish MLP (MFMA, rows 0..3 of 16-row tile) + LN.

typedef unsigned long long u64;
typedef unsigned short u16;
typedef __attribute__((ext_vector_type(8))) unsigned short us8;
typedef __attribute__((ext_vector_type(4))) unsigned short us4;
typedef __attribute__((ext_vector_type(8))) short s8;
typedef __attribute__((ext_vector_type(4))) float f4;

__device__ __forceinline__ float eluf(float v) { return v > 0.f ? v : expm1f(v); }
__device__ __forceinline__ float mishf(float v) {
  float sp = fmaxf(v, 0.f) + log1pf(expf(-fabsf(v)));
  return v * tanhf(sp);
}
__device__ __forceinline__ u16 f2bf(float f) {
  unsigned u = __float_as_uint(f);
  unsigned r = u + 0x7FFFu + ((u >> 16) & 1u);
  return (u16)(r >> 16);
}
__device__ __forceinline__ float bf2f(u16 h) { return __uint_as_float((unsigned)h << 16); }

__device__ __forceinline__ f4 mfma16(const u16* a, const u16* b, f4 c) {
  s8 av = *(const s8*)(const void*)a;
  s8 bv = *(const s8*)(const void*)b;
  return __builtin_amdgcn_mfma_f32_16x16x32_bf16(av, bv, c, 0, 0, 0);
}

__device__ __forceinline__ u64 expand32(u64 x) {
  x &= 0xFFFFFFFFull;
  x = (x | (x << 16)) & 0x0000FFFF0000FFFFull;
  x = (x | (x << 8))  & 0x00FF00FF00FF00FFull;
  x = (x | (x << 4))  & 0x0F0F0F0F0F0F0F0Full;
  x = (x | (x << 2))  & 0x3333333333333333ull;
  x = (x | (x << 1))  & 0x5555555555555555ull;
  return x | (x << 1);
}

__device__ __forceinline__ us8 cvt8(const float* p) {
  float4 a = *(const float4*)p;
  float4 b = *(const float4*)(p + 4);
  us8 v;
  v[0] = f2bf(a.x); v[1] = f2bf(a.y); v[2] = f2bf(a.z); v[3] = f2bf(a.w);
  v[4] = f2bf(b.x); v[5] = f2bf(b.y); v[6] = f2bf(b.z); v[7] = f2bf(b.w);
  return v;
}

// ---- K1: blocks 0..255: K=elu(xWk^T) Q=elu(xWq^T) V=xWv^T SKP=xWskip^T+b,
//      Kpart[nt][row] partial rowsums of K.  Block 256: bitpacked mask -> Mb.
__global__ __launch_bounds__(256) void qkvs_mask(const float* __restrict__ x,
    const float* __restrict__ Wk, const float* __restrict__ Wq,
    const float* __restrict__ Wv, const float* __restrict__ Wsk,
    const float* __restrict__ bskip,
    const int* __restrict__ start, const int* __restrict__ done,
    u16* __restrict__ Kb, u16* __restrict__ Qb, u16* __restrict__ Vb,
    float* __restrict__ SKP, float* __restrict__ Kpart, u64* __restrict__ Mb) {
  __shared__ u64 SMEM[5810];  // union: GEMM {Xs,Ws} 10KB | mask {LV,sB,dB} 46.4KB
  const int tid = threadIdx.x;
  if (blockIdx.x < 256) {
    u16* Xs = (u16*)SMEM;          // 64x40
    u16* Ws = Xs + 2560;           // 64x40
    const int wave = tid >> 6, l = tid & 63;
    const int l15 = l & 15, quad = l >> 4;
    const int rt = blockIdx.x & 15, my = blockIdx.x >> 4;
    const int mat = my >> 2, nt = my & 3;
    const int n0 = nt * 64, mbase = rt * 64;
    const float* Wsrc = (mat == 0) ? Wk : (mat == 1) ? Wq : (mat == 2) ? Wv : Wsk;
    f4 acc[4];
#pragma unroll
    for (int s = 0; s < 4; s++) acc[s] = (f4){0.f, 0.f, 0.f, 0.f};
    const int srow = tid >> 2, sko = (tid & 3) * 8;
    for (int kt = 0; kt < 8; kt++) {
      *(us8*)&Xs[srow * 40 + sko] = cvt8(&x[(mbase + srow) * 256 + kt * 32 + sko]);
      *(us8*)&Ws[srow * 40 + sko] = cvt8(&Wsrc[(n0 + srow) * 256 + kt * 32 + sko]);
      __syncthreads();
      const u16* ap = &Xs[(wave * 16 + l15) * 40 + quad * 8];
#pragma unroll
      for (int s = 0; s < 4; s++)
        acc[s] = mfma16(ap, &Ws[(s * 16 + l15) * 40 + quad * 8], acc[s]);
      __syncthreads();
    }
    const int mw = mbase + wave * 16 + quad * 4;
    if (mat == 0) {
      float tmp[4][4];
#pragma unroll
      for (int s = 0; s < 4; s++)
#pragma unroll
        for (int r = 0; r < 4; r++) {
          float v = eluf(acc[s][r]);
          tmp[s][r] = v;
          Kb[(mw + r) * 256 + n0 + s * 16 + l15] = f2bf(v);
        }
#pragma unroll
      for (int r = 0; r < 4; r++) {
        float t = tmp[0][r] + tmp[1][r] + tmp[2][r] + tmp[3][r];
#pragma unroll
        for (int off = 1; off <= 8; off <<= 1) t += __shfl_xor(t, off);
        if (l15 == 0) Kpart[nt * 1024 + mw + r] = t;
      }
    } else if (mat == 1) {
#pragma unroll
      for (int s = 0; s < 4; s++)
#pragma unroll
        for (int r = 0; r < 4; r++)
          Qb[(mw + r) * 256 + n0 + s * 16 + l15] = f2bf(eluf(acc[s][r]));
    } else if (mat == 2) {
#pragma unroll
      for (int s = 0; s < 4; s++)
#pragma unroll
        for (int r = 0; r < 4; r++)
          Vb[(mw + r) * 256 + n0 + s * 16 + l15] = f2bf(acc[s][r]);
    } else {
#pragma unroll
      for (int s = 0; s < 4; s++) {
        int n = n0 + s * 16 + l15;
        float bv = bskip[n];
#pragma unroll
        for (int r = 0; r < 4; r++)
          SKP[(mw + r) * 256 + n] = acc[s][r] + bv;
      }
    }
    return;
  }
  // ---- mask block (256-thread port of proven R3 mask_bits) ----
  u64* LV = SMEM;
  unsigned char* sB = (unsigned char*)(SMEM + 5540);
  unsigned char* dB = sB + 1028;
  for (int i = tid; i < 1025; i += 256) {
    sB[i] = (unsigned char)(start[i] != 0);
    dB[i] = (unsigned char)(done[i] != 0);
  }
  if (tid == 0) LV[0] = 1ull;  // level 10: W[0][0]=1
  __syncthreads();
  const int LOFF[11] = {0, 1407, 383, 127, 63, 31, 15, 7, 3, 1, 0};
  const int GOFF[10] = {5503, 5520, 5528, 5532, 5534, 5535, 5536, 5537, 5538, 5539};
  if (tid < 37) {
    int lv, w;
    if (tid < 17)      { lv = 0; w = tid; }
    else if (tid < 25) { lv = 1; w = tid - 17; }
    else if (tid < 29) { lv = 2; w = tid - 25; }
    else if (tid < 31) { lv = 3; w = tid - 29; }
    else               { lv = tid - 27; w = 0; }
    int n = 1024 >> lv;
    u64 g = 0;
    for (int b = 0; b < 64; b++) {
      int j = (w << 6) + b;
      if (j >= n) break;
      unsigned char bit = (j & 1) ? dB[((j + 1) << lv) - 1] : sB[((j + 2) << lv) - 1];
      g |= (u64)bit << b;
    }
    LV[GOFF[lv] + w] = g;
  }
  __syncthreads();
#pragma unroll
  for (int lv = 9; lv >= 1; lv--) {
    const int n = 1024 >> lv;
    const int nw = (n >= 64) ? (n >> 6) : 1;
    const int nwp = (n >= 128) ? (n >> 7) : 1;
    const int total = n * nw;
    for (int idx = tid; idx < total; idx += 256) {
      int t = idx / nw, w = idx - t * nw;
      u64 word;
      if (t == 0) word = (w == 0) ? 1ull : 0ull;
      else {
        int p = (t & 1) ? (t >> 1) : (t >> 1) - 1;
        u64 pw = LV[LOFF[lv + 1] + p * nwp + (w >> 1)];
        u64 e = expand32((w & 1) ? (pw >> 32) : pw) & LV[GOFF[lv] + w];
        if (t & 1) word = e;
        else {
          int gi = ((t + 1) << lv) - 1;
          word = sB[gi] ? e : 0ull;
          if ((t >> 6) == w) word |= (u64)dB[gi] << (t & 63);
        }
      }
      LV[LOFF[lv] + t * nw + w] = word;
    }
    __syncthreads();
  }
  for (int idx = tid; idx < 1024 * 16; idx += 256) {
    int tp = idx >> 4, wp = idx & 15;
    int t = tp + 1;
    int p = (t & 1) ? (t >> 1) : (t >> 1) - 1;
    u64 sw[2];
#pragma unroll
    for (int u = 0; u < 2; u++) {
      int w = wp + u;
      u64 e = 0;
      if (w < 16) {
        u64 pw = LV[1407 + p * 8 + (w >> 1)];
        e = expand32((w & 1) ? (pw >> 32) : pw) & LV[GOFF[0] + w];
      }
      if (t & 1) sw[u] = e;
      else {
        u64 word = sB[t] ? e : 0ull;
        if ((t >> 6) == w) word |= (u64)dB[t] << (t & 63);
        sw[u] = word;
      }
    }
    Mb[tp * 16 + wp] = (sw[0] >> 1) | (sw[1] << 63);
  }
}

// ---- K2: sparse attention + fused MLP + LN. grid(256) x 512 (8 waves).
// 4 rows/block; waves r and r+4 split row r's 16 mask words.
__global__ __launch_bounds__(512) void attn_mlp(
    const u16* __restrict__ Kb, const u16* __restrict__ Qb, const u16* __restrict__ Vb,
    const float* __restrict__ Kpart, const float* __restrict__ SKP,
    const u64* __restrict__ Mb,
    const float* __restrict__ W1, const float* __restrict__ W2, const float* __restrict__ W3,
    const float* __restrict__ b1, const float* __restrict__ b2, const float* __restrict__ b3,
    const float* __restrict__ lnw, const float* __restrict__ lnb,
    float* __restrict__ outp) {
  __shared__ float Ks[1024];
  __shared__ u64 Mw[64];
  __shared__ u16 As[16 * 264];      // rows 0..3 valid (A-rows 4..15 garbage: harmless)
  __shared__ float Op[8][256];
  __shared__ float dp[8];
  __shared__ u16 WsAll[8 * 640];
  __shared__ float Hbuf[4 * 260];
  const int tid = threadIdx.x, wave = tid >> 6, l = tid & 63;
  const int l15 = l & 15, quad = l >> 4;
  const int m0 = blockIdx.x * 4;
  // preamble: Ksum = sum of 4 partials; mask rows
  {
    int j = tid * 2;
    Ks[j] = Kpart[j] + Kpart[1024 + j] + Kpart[2048 + j] + Kpart[3072 + j];
    Ks[j + 1] = Kpart[j + 1] + Kpart[1024 + j + 1] + Kpart[2048 + j + 1] + Kpart[3072 + j + 1];
    if (tid < 64) Mw[tid] = Mb[(m0 + (tid >> 4)) * 16 + (tid & 15)];
  }
  __syncthreads();
  // phase B: sparse gather
  const int r = wave & 3, h = wave >> 2;
  const int tp = m0 + r;
  float q[4], O[4] = {0.f, 0.f, 0.f, 0.f};
  {
    us4 qv = *(const us4*)&Qb[tp * 256 + l * 4];
    q[0] = bf2f(qv.x); q[1] = bf2f(qv.y); q[2] = bf2f(qv.z); q[3] = bf2f(qv.w);
  }
  float qs = q[0] + q[1] + q[2] + q[3];
#pragma unroll
  for (int off = 1; off <= 32; off <<= 1) qs += __shfl_xor(qs, off);
  float d = 0.f;
  for (int w = h * 8; w < h * 8 + 8; w++) {
    u64 bits = Mw[r * 16 + w];
    while (bits) {
      int b = __builtin_ctzll(bits);
      bits &= bits - 1;
      int j = w * 64 + b;
      us4 kv = *(const us4*)&Kb[j * 256 + l * 4];
      us4 vv = *(const us4*)&Vb[j * 256 + l * 4];
      float s = q[0] * bf2f(kv.x) + q[1] * bf2f(kv.y) + q[2] * bf2f(kv.z) + q[3] * bf2f(kv.w);
#pragma unroll
      for (int off = 1; off <= 32; off <<= 1) s += __shfl_xor(s, off);
      d += Ks[j];
      O[0] += s * bf2f(vv.x); O[1] += s * bf2f(vv.y);
      O[2] += s * bf2f(vv.z); O[3] += s * bf2f(vv.w);
    }
  }
#pragma unroll
  for (int i = 0; i < 4; i++) Op[wave][l * 4 + i] = O[i];
  if (l == 0) dp[wave] = d;
  __syncthreads();
  if (h == 0) {
    float dd = dp[r] + dp[r + 4];
    float inv = 1.f / fmaxf(qs * dd, 1e-5f);
    us4 o;
    o.x = f2bf((O[0] + Op[r + 4][l * 4 + 0]) * inv);
    o.y = f2bf((O[1] + Op[r + 4][l * 4 + 1]) * inv);
    o.z = f2bf((O[2] + Op[r + 4][l * 4 + 2]) * inv);
    o.w = f2bf((O[3] + Op[r + 4][l * 4 + 3]) * inv);
    *(us4*)&As[r * 264 + l * 4] = o;
  }
  __syncthreads();
  // phase C: 3-layer mish MLP via MFMA; wave handles col-tiles 2*wave, 2*wave+1
  u16* Wsw = WsAll + wave * 640;
  const int wr = l >> 2, wko = (l & 3) * 8;
#pragma unroll 1
  for (int layer = 0; layer < 3; layer++) {
    const float* Wl = (layer == 0) ? W1 : (layer == 1) ? W2 : W3;
    const float* bias = (layer == 0) ? b1 : (layer == 1) ? b2 : b3;
    f4 acc[2];
#pragma unroll
    for (int c = 0; c < 2; c++) {
      const int nt = wave * 2 + c;
      acc[c] = (f4){0.f, 0.f, 0.f, 0.f};
      for (int kt = 0; kt < 8; kt++) {
        *(us8*)&Wsw[wr * 40 + wko] = cvt8(&Wl[(nt * 16 + wr) * 256 + kt * 32 + wko]);
        const u16* ap = &As[l15 * 264 + kt * 32 + quad * 8];
        acc[c] = mfma16(ap, &Wsw[l15 * 40 + quad * 8], acc[c]);
      }
    }
    __syncthreads();  // all waves done reading As
    if (quad == 0) {
#pragma unroll
      for (int c = 0; c < 2; c++) {
        const int n = (wave * 2 + c) * 16 + l15;
        float bv = bias[n];
        if (layer < 2) {
#pragma unroll
          for (int rr = 0; rr < 4; rr++)
            As[rr * 264 + n] = f2bf(mishf(acc[c][rr] + bv));
        } else {
#pragma unroll
          for (int rr = 0; rr < 4; rr++)
            Hbuf[rr * 260 + n] = acc[c][rr] + bv + SKP[(m0 + rr) * 256 + n];
        }
      }
    }
    __syncthreads();
  }
  // LayerNorm: waves 0..3 = rows
  if (wave < 4) {
    float hv[4];
#pragma unroll
    for (int i = 0; i < 4; i++) hv[i] = Hbuf[wave * 260 + l * 4 + i];
    float s1 = hv[0] + hv[1] + hv[2] + hv[3];
    float s2 = hv[0] * hv[0] + hv[1] * hv[1] + hv[2] * hv[2] + hv[3] * hv[3];
#pragma unroll
    for (int off = 1; off <= 32; off <<= 1) {
      s1 += __shfl_xor(s1, off);
      s2 += __shfl_xor(s2, off);
    }
    float mu = s1 * (1.f / 256.f);
    float var = s2 * (1.f / 256.f) - mu * mu;
    float rs = rsqrtf(fmaxf(var, 0.f) + 1e-5f);
    float4 wv = *(const float4*)&lnw[l * 4];
    float4 bv = *(const float4*)&lnb[l * 4];
    float4 o;
    o.x = (hv[0] - mu) * rs * wv.x + bv.x;
    o.y = (hv[1] - mu) * rs * wv.y + bv.y;
    o.z = (hv[2] - mu) * rs * wv.z + bv.z;
    o.w = (hv[3] - mu) * rs * wv.w + bv.w;
    *(float4*)&outp[(m0 + wave) * 256 + l * 4] = o;
  }
}

extern "C" void kernel_launch(void* const* d_in, const int* in_sizes, int n_in,
                              void* d_out, int out_size, void* d_ws, size_t ws_size,
                              hipStream_t stream) {
  (void)in_sizes; (void)n_in; (void)out_size; (void)ws_size;
  const float* x   = (const float*)d_in[0];
  const int* start = (const int*)d_in[3];
  const int* done  = (const int*)d_in[4];
  const float* Wk  = (const float*)d_in[5];
  const float* Wq  = (const float*)d_in[6];
  const float* Wv  = (const float*)d_in[7];
  const float* Wsk = (const float*)d_in[8];
  const float* bsk = (const float*)d_in[9];
  const float* W1  = (const float*)d_in[10];
  const float* b1  = (const float*)d_in[11];
  const float* W2  = (const float*)d_in[12];
  const float* b2  = (const float*)d_in[13];
  const float* W3  = (const float*)d_in[14];
  const float* b3  = (const float*)d_in[15];
  const float* lnw = (const float*)d_in[16];
  const float* lnb = (const float*)d_in[17];
  float* out = (float*)d_out;

  char* w = (char*)d_ws;
  u16* Kb      = (u16*)w;                  // 1024x256 bf16
  u16* Qb      = (u16*)(w + 524288);
  u16* Vb      = (u16*)(w + 1048576);
  float* SKP   = (float*)(w + 1572864);    // 1024x256 fp32
  float* Kpart = (float*)(w + 2621440);    // 4x1024 fp32
  u64* Mb      = (u64*)(w + 2637824);      // 1024x16 u64

  qkvs_mask<<<257, 256, 0, stream>>>(x, Wk, Wq, Wv, Wsk, bsk, start, done,
                                     Kb, Qb, Vb, SKP, Kpart, Mb);
  attn_mlp<<<256, 512, 0, stream>>>(Kb, Qb, Vb, Kpart, SKP, Mb,
                                    W1, W2, W3, b1, b2, b3, lnw, lnb, out);
}

// Round 8
// 133.488 us; speedup vs baseline: 1.1950x; 1.1950x over previous
//
#include <hip/hip_runtime.h>
#include <math.h>

// LinearAttention: T=1024, D=256, H=256.  R8: 2 kernels, no mask dispatch.
// combine() is NOT associative; replicate JAX's odd-even bracketing.
// s0=z0=0 -> s_t = sum_j W[t][j] k_j v_j^T; denom_t = (sum_j W[t][j] Ksum_j)*Qsum_t.
// R7 lesson: a 256-thr mask block serialized a whole dispatch (45 us tail).
// R8: K2 derives ITS OWN 4 mask rows from start/done: gates via __ballot
// (bit-per-lane), per-row ancestor chain (levels 9..1, ~20 u64 words) walked
// top-down, level-0 words in-register (R6-proven formula). No Mb anywhere.
// K1 = pure qkvs MFMA projections (R6/R7-proven body, 10KB LDS, Kpart).

typedef unsigned long long u64;
typedef unsigned short u16;
typedef __attribute__((ext_vector_type(8))) unsigned short us8;
typedef __attribute__((ext_vector_type(4))) unsigned short us4;
typedef __attribute__((ext_vector_type(8))) short s8;
typedef __attribute__((ext_vector_type(4))) float f4;

__device__ __forceinline__ float eluf(float v) { return v > 0.f ? v : expm1f(v); }
__device__ __forceinline__ float mishf(float v) {
  float sp = fmaxf(v, 0.f) + log1pf(expf(-fabsf(v)));
  return v * tanhf(sp);
}
__device__ __forceinline__ u16 f2bf(float f) {
  unsigned u = __float_as_uint(f);
  unsigned r = u + 0x7FFFu + ((u >> 16) & 1u);
  return (u16)(r >> 16);
}
__device__ __forceinline__ float bf2f(u16 h) { return __uint_as_float((unsigned)h << 16); }

__device__ __forceinline__ f4 mfma16(const u16* a, const u16* b, f4 c) {
  s8 av = *(const s8*)(const void*)a;
  s8 bv = *(const s8*)(const void*)b;
  return __builtin_amdgcn_mfma_f32_16x16x32_bf16(av, bv, c, 0, 0, 0);
}

__device__ __forceinline__ u64 expand32(u64 x) {
  x &= 0xFFFFFFFFull;
  x = (x | (x << 16)) & 0x0000FFFF0000FFFFull;
  x = (x | (x << 8))  & 0x00FF00FF00FF00FFull;
  x = (x | (x << 4))  & 0x0F0F0F0F0F0F0F0Full;
  x = (x | (x << 2))  & 0x3333333333333333ull;
  x = (x | (x << 1))  & 0x5555555555555555ull;
  return x | (x << 1);
}

__device__ __forceinline__ us8 cvt8(const float* p) {
  float4 a = *(const float4*)p;
  float4 b = *(const float4*)(p + 4);
  us8 v;
  v[0] = f2bf(a.x); v[1] = f2bf(a.y); v[2] = f2bf(a.z); v[3] = f2bf(a.w);
  v[4] = f2bf(b.x); v[5] = f2bf(b.y); v[6] = f2bf(b.z); v[7] = f2bf(b.w);
  return v;
}

// ---- K1: K=elu(xWk^T) Q=elu(xWq^T) V=xWv^T SKP=xWskip^T+b, Kpart rowsums.
// grid(256): rt = blk&15, (mat,nt) = blk>>4.  (R6/R7-proven body.)
__global__ __launch_bounds__(256) void qkvs_mfma(const float* __restrict__ x,
    const float* __restrict__ Wk, const float* __restrict__ Wq,
    const float* __restrict__ Wv, const float* __restrict__ Wsk,
    const float* __restrict__ bskip,
    u16* __restrict__ Kb, u16* __restrict__ Qb, u16* __restrict__ Vb,
    float* __restrict__ SKP, float* __restrict__ Kpart) {
  __shared__ u16 Xs[64 * 40], Ws[64 * 40];
  const int tid = threadIdx.x, wave = tid >> 6, l = tid & 63;
  const int l15 = l & 15, quad = l >> 4;
  const int rt = blockIdx.x & 15, my = blockIdx.x >> 4;
  const int mat = my >> 2, nt = my & 3;
  const int n0 = nt * 64, mbase = rt * 64;
  const float* Wsrc = (mat == 0) ? Wk : (mat == 1) ? Wq : (mat == 2) ? Wv : Wsk;
  f4 acc[4];
#pragma unroll
  for (int s = 0; s < 4; s++) acc[s] = (f4){0.f, 0.f, 0.f, 0.f};
  const int srow = tid >> 2, sko = (tid & 3) * 8;
  for (int kt = 0; kt < 8; kt++) {
    *(us8*)&Xs[srow * 40 + sko] = cvt8(&x[(mbase + srow) * 256 + kt * 32 + sko]);
    *(us8*)&Ws[srow * 40 + sko] = cvt8(&Wsrc[(n0 + srow) * 256 + kt * 32 + sko]);
    __syncthreads();
    const u16* ap = &Xs[(wave * 16 + l15) * 40 + quad * 8];
#pragma unroll
    for (int s = 0; s < 4; s++)
      acc[s] = mfma16(ap, &Ws[(s * 16 + l15) * 40 + quad * 8], acc[s]);
    __syncthreads();
  }
  const int mw = mbase + wave * 16 + quad * 4;
  if (mat == 0) {
    float tmp[4][4];
#pragma unroll
    for (int s = 0; s < 4; s++)
#pragma unroll
      for (int r = 0; r < 4; r++) {
        float v = eluf(acc[s][r]);
        tmp[s][r] = v;
        Kb[(mw + r) * 256 + n0 + s * 16 + l15] = f2bf(v);
      }
#pragma unroll
    for (int r = 0; r < 4; r++) {
      float t = tmp[0][r] + tmp[1][r] + tmp[2][r] + tmp[3][r];
#pragma unroll
      for (int off = 1; off <= 8; off <<= 1) t += __shfl_xor(t, off);
      if (l15 == 0) Kpart[nt * 1024 + mw + r] = t;
    }
  } else if (mat == 1) {
#pragma unroll
    for (int s = 0; s < 4; s++)
#pragma unroll
      for (int r = 0; r < 4; r++)
        Qb[(mw + r) * 256 + n0 + s * 16 + l15] = f2bf(eluf(acc[s][r]));
  } else if (mat == 2) {
#pragma unroll
    for (int s = 0; s < 4; s++)
#pragma unroll
      for (int r = 0; r < 4; r++)
        Vb[(mw + r) * 256 + n0 + s * 16 + l15] = f2bf(acc[s][r]);
  } else {
#pragma unroll
    for (int s = 0; s < 4; s++) {
      int n = n0 + s * 16 + l15;
      float bv = bskip[n];
#pragma unroll
      for (int r = 0; r < 4; r++)
        SKP[(mw + r) * 256 + n] = acc[s][r] + bv;
    }
  }
}

// ---- K2: mask rows (self-derived) + sparse attention + fused MLP + LN.
// grid(256) x 512 (8 waves). 4 rows/block; waves r and r+4 split row r.
__global__ __launch_bounds__(512) void attn_mlp(
    const u16* __restrict__ Kb, const u16* __restrict__ Qb, const u16* __restrict__ Vb,
    const float* __restrict__ Kpart, const float* __restrict__ SKP,
    const int* __restrict__ start, const int* __restrict__ done,
    const float* __restrict__ W1, const float* __restrict__ W2, const float* __restrict__ W3,
    const float* __restrict__ b1, const float* __restrict__ b2, const float* __restrict__ b3,
    const float* __restrict__ lnw, const float* __restrict__ lnb,
    float* __restrict__ outp) {
  __shared__ float Ks[1024];
  __shared__ unsigned char sBs[1028], dBs[1028];
  __shared__ u64 GS[37];        // gates: G0@0(17) G1@17(8) G2@25(4) G3@29(2) G4..G9@31..36
  __shared__ u64 CH[4][21];     // per-row chain: l=1@0(8) 2@8(4) 3@12(2) 4..10@14..20
  __shared__ u64 Mw[64];
  __shared__ u16 As[16 * 264];
  __shared__ float Op[8][256];
  __shared__ float dp[8];
  __shared__ u16 WsAll[8 * 640];
  __shared__ float Hbuf[4 * 260];
  const int tid = threadIdx.x, wave = tid >> 6, l = tid & 63;
  const int l15 = l & 15, quad = l >> 4;
  const int m0 = blockIdx.x * 4;
  // stage start/done + Ksum preamble
  for (int i = tid; i < 1025; i += 512) {
    sBs[i] = (unsigned char)(start[i] != 0);
    dBs[i] = (unsigned char)(done[i] != 0);
  }
  {
    int j = tid * 2;
    Ks[j] = Kpart[j] + Kpart[1024 + j] + Kpart[2048 + j] + Kpart[3072 + j];
    Ks[j + 1] = Kpart[j + 1] + Kpart[1024 + j + 1] + Kpart[2048 + j + 1] + Kpart[3072 + j + 1];
  }
  if (wave < 4 && l == 0) CH[wave][20] = 1ull;  // level 10 row 0 = [1]
  __syncthreads();
  // gates via ballot: waves 4..7 handle jobs (wave-4), (wave-4)+4, ...
  if (wave >= 4) {
    for (int job = wave - 4; job < 37; job += 4) {
      int lv, w;
      if (job < 17)      { lv = 0; w = job; }
      else if (job < 25) { lv = 1; w = job - 17; }
      else if (job < 29) { lv = 2; w = job - 25; }
      else if (job < 31) { lv = 3; w = job - 29; }
      else               { lv = job - 27; w = 0; }
      int n = 1024 >> lv;
      int j = w * 64 + l;
      int ok = 0;
      if (j < n)
        ok = (j & 1) ? dBs[((j + 1) << lv) - 1] : sBs[((j + 2) << lv) - 1];
      u64 word = __ballot(ok != 0);
      if (l == 0) GS[(lv == 0) ? w : (lv == 1) ? 17 + w : (lv == 2) ? 25 + w
                     : (lv == 3) ? 29 + w : 27 + lv] = word;
    }
  }
  __syncthreads();
  // ancestor chains, top-down. wave c (<4) = row t0 = m0+c+1; lane w = word.
  const int CHOFF[11] = {0, 0, 8, 12, 14, 15, 16, 17, 18, 19, 20};
  const int GOFF2[10] = {0, 17, 25, 29, 31, 32, 33, 34, 35, 36};
#pragma unroll 1
  for (int lv = 9; lv >= 1; lv--) {
    if (wave < 4) {
      int nw = (1024 >> lv) >= 64 ? ((1024 >> lv) >> 6) : 1;
      if (l < nw) {
        int rr = m0 + wave + 1;
        for (int q = 0; q < lv; q++) rr = (rr & 1) ? (rr >> 1) : (rr >> 1) - 1;
        u64 word;
        if (rr <= 0) word = (l == 0 && rr == 0) ? 1ull : 0ull;
        else {
          u64 pw = CH[wave][CHOFF[lv + 1] + (l >> 1)];
          u64 e = expand32((l & 1) ? (pw >> 32) : pw) & GS[GOFF2[lv] + l];
          if (rr & 1) word = e;
          else {
            int gi = ((rr + 1) << lv) - 1;
            word = sBs[gi] ? e : 0ull;
            if ((rr >> 6) == l) word |= (u64)dBs[gi] << (rr & 63);
          }
        }
        CH[wave][CHOFF[lv] + l] = word;
      }
    }
    __syncthreads();
  }
  // level-0 words (shifted by 1 bit; drop leaf 0 = s0). wave c, lanes 0..16.
  if (wave < 4) {
    const int t = m0 + wave + 1;
    u64 uw = 0;
    if (l <= 16) {
      u64 e = 0;
      if (l < 16) {
        u64 pw = CH[wave][(l >> 1)];   // level-1 row (= parent of t)
        e = expand32((l & 1) ? (pw >> 32) : pw) & GS[l];
      }
      if (t & 1) uw = e;
      else {
        uw = sBs[t] ? e : 0ull;
        if ((t >> 6) == l) uw |= (u64)dBs[t] << (t & 63);
      }
    }
    u64 nxt = __shfl(uw, (l + 1) & 63);
    u64 mw0 = (uw >> 1) | (nxt << 63);
    if (l < 16) Mw[wave * 16 + l] = mw0;
  }
  __syncthreads();
  // phase B: sparse gather (R7-proven)
  const int r = wave & 3, h = wave >> 2;
  const int tp = m0 + r;
  float q[4], O[4] = {0.f, 0.f, 0.f, 0.f};
  {
    us4 qv = *(const us4*)&Qb[tp * 256 + l * 4];
    q[0] = bf2f(qv.x); q[1] = bf2f(qv.y); q[2] = bf2f(qv.z); q[3] = bf2f(qv.w);
  }
  float qs = q[0] + q[1] + q[2] + q[3];
#pragma unroll
  for (int off = 1; off <= 32; off <<= 1) qs += __shfl_xor(qs, off);
  float d = 0.f;
  for (int w = h * 8; w < h * 8 + 8; w++) {
    u64 bits = Mw[r * 16 + w];
    while (bits) {
      int b = __builtin_ctzll(bits);
      bits &= bits - 1;
      int j = w * 64 + b;
      us4 kv = *(const us4*)&Kb[j * 256 + l * 4];
      us4 vv = *(const us4*)&Vb[j * 256 + l * 4];
      float s = q[0] * bf2f(kv.x) + q[1] * bf2f(kv.y) + q[2] * bf2f(kv.z) + q[3] * bf2f(kv.w);
#pragma unroll
      for (int off = 1; off <= 32; off <<= 1) s += __shfl_xor(s, off);
      d += Ks[j];
      O[0] += s * bf2f(vv.x); O[1] += s * bf2f(vv.y);
      O[2] += s * bf2f(vv.z); O[3] += s * bf2f(vv.w);
    }
  }
#pragma unroll
  for (int i = 0; i < 4; i++) Op[wave][l * 4 + i] = O[i];
  if (l == 0) dp[wave] = d;
  __syncthreads();
  if (h == 0) {
    float dd = dp[r] + dp[r + 4];
    float inv = 1.f / fmaxf(qs * dd, 1e-5f);
    us4 o;
    o.x = f2bf((O[0] + Op[r + 4][l * 4 + 0]) * inv);
    o.y = f2bf((O[1] + Op[r + 4][l * 4 + 1]) * inv);
    o.z = f2bf((O[2] + Op[r + 4][l * 4 + 2]) * inv);
    o.w = f2bf((O[3] + Op[r + 4][l * 4 + 3]) * inv);
    *(us4*)&As[r * 264 + l * 4] = o;
  }
  __syncthreads();
  // phase C: 3-layer mish MLP via MFMA (R7-proven); wave = col-tiles 2w,2w+1
  u16* Wsw = WsAll + wave * 640;
  const int wr = l >> 2, wko = (l & 3) * 8;
#pragma unroll 1
  for (int layer = 0; layer < 3; layer++) {
    const float* Wl = (layer == 0) ? W1 : (layer == 1) ? W2 : W3;
    const float* bias = (layer == 0) ? b1 : (layer == 1) ? b2 : b3;
    f4 acc[2];
#pragma unroll
    for (int c = 0; c < 2; c++) {
      const int nt = wave * 2 + c;
      acc[c] = (f4){0.f, 0.f, 0.f, 0.f};
      for (int kt = 0; kt < 8; kt++) {
        *(us8*)&Wsw[wr * 40 + wko] = cvt8(&Wl[(nt * 16 + wr) * 256 + kt * 32 + wko]);
        const u16* ap = &As[l15 * 264 + kt * 32 + quad * 8];
        acc[c] = mfma16(ap, &Wsw[l15 * 40 + quad * 8], acc[c]);
      }
    }
    __syncthreads();
    if (quad == 0) {
#pragma unroll
      for (int c = 0; c < 2; c++) {
        const int n = (wave * 2 + c) * 16 + l15;
        float bv = bias[n];
        if (layer < 2) {
#pragma unroll
          for (int rr = 0; rr < 4; rr++)
            As[rr * 264 + n] = f2bf(mishf(acc[c][rr] + bv));
        } else {
#pragma unroll
          for (int rr = 0; rr < 4; rr++)
            Hbuf[rr * 260 + n] = acc[c][rr] + bv + SKP[(m0 + rr) * 256 + n];
        }
      }
    }
    __syncthreads();
  }
  // LayerNorm: waves 0..3 = rows
  if (wave < 4) {
    float hv[4];
#pragma unroll
    for (int i = 0; i < 4; i++) hv[i] = Hbuf[wave * 260 + l * 4 + i];
    float s1 = hv[0] + hv[1] + hv[2] + hv[3];
    float s2 = hv[0] * hv[0] + hv[1] * hv[1] + hv[2] * hv[2] + hv[3] * hv[3];
#pragma unroll
    for (int off = 1; off <= 32; off <<= 1) {
      s1 += __shfl_xor(s1, off);
      s2 += __shfl_xor(s2, off);
    }
    float mu = s1 * (1.f / 256.f);
    float var = s2 * (1.f / 256.f) - mu * mu;
    float rs = rsqrtf(fmaxf(var, 0.f) + 1e-5f);
    float4 wv = *(const float4*)&lnw[l * 4];
    float4 bv = *(const float4*)&lnb[l * 4];
    float4 o;
    o.x = (hv[0] - mu) * rs * wv.x + bv.x;
    o.y = (hv[1] - mu) * rs * wv.y + bv.y;
    o.z = (hv[2] - mu) * rs * wv.z + bv.z;
    o.w = (hv[3] - mu) * rs * wv.w + bv.w;
    *(float4*)&outp[(m0 + wave) * 256 + l * 4] = o;
  }
}

extern "C" void kernel_launch(void* const* d_in, const int* in_sizes, int n_in,
                              void* d_out, int out_size, void* d_ws, size_t ws_size,
                              hipStream_t stream) {
  (void)in_sizes; (void)n_in; (void)out_size; (void)ws_size;
  const float* x   = (const float*)d_in[0];
  const int* start = (const int*)d_in[3];
  const int* done  = (const int*)d_in[4];
  const float* Wk  = (const float*)d_in[5];
  const float* Wq  = (const float*)d_in[6];
  const float* Wv  = (const float*)d_in[7];
  const float* Wsk = (const float*)d_in[8];
  const float* bsk = (const float*)d_in[9];
  const float* W1  = (const float*)d_in[10];
  const float* b1  = (const float*)d_in[11];
  const float* W2  = (const float*)d_in[12];
  const float* b2  = (const float*)d_in[13];
  const float* W3  = (const float*)d_in[14];
  const float* b3  = (const float*)d_in[15];
  const float* lnw = (const float*)d_in[16];
  const float* lnb = (const float*)d_in[17];
  float* out = (float*)d_out;

  char* w = (char*)d_ws;
  u16* Kb      = (u16*)w;                  // 1024x256 bf16
  u16* Qb      = (u16*)(w + 524288);
  u16* Vb      = (u16*)(w + 1048576);
  float* SKP   = (float*)(w + 1572864);    // 1024x256 fp32
  float* Kpart = (float*)(w + 2621440);    // 4x1024 fp32

  qkvs_mfma<<<256, 256, 0, stream>>>(x, Wk, Wq, Wv, Wsk, bsk, Kb, Qb, Vb, SKP, Kpart);
  attn_mlp<<<256, 512, 0, stream>>>(Kb, Qb, Vb, Kpart, SKP, start, done,
                                    W1, W2, W3, b1, b2, b3, lnw, lnb, out);
}